// Round 1
// baseline (874.688 us; speedup 1.0000x reference)
//
#include <hip/hip_runtime.h>
#include <stdint.h>

#define BN_EPS 1e-5f
#define ST 264   // LDS row stride in bf16 elems: rows 16B-aligned, bank-skewed

typedef __bf16 bf16x8 __attribute__((ext_vector_type(8)));
typedef float  f32x4  __attribute__((ext_vector_type(4)));

__device__ __forceinline__ unsigned short f2bf(float f) {
    unsigned u = __float_as_uint(f);
    unsigned r = (u + 0x7FFFu + ((u >> 16) & 1u)) >> 16;
    return (unsigned short)r;
}
__device__ __forceinline__ unsigned pk2(float a, float b) {
    return (unsigned)f2bf(a) | ((unsigned)f2bf(b) << 16);
}
// order-preserving float -> uint key (monotone for all finite floats)
__device__ __forceinline__ unsigned fkey(float f) {
    unsigned b = __float_as_uint(f);
    return (b & 0x80000000u) ? ~b : (b | 0x80000000u);
}
__device__ __forceinline__ float unkey(unsigned u) {
    unsigned b = (u & 0x80000000u) ? (u ^ 0x80000000u) : ~u;
    return __uint_as_float(b);
}

__global__ void prep_kernel(
    const float* __restrict__ W1, const float* __restrict__ W2, const float* __restrict__ W3,
    const float* __restrict__ b1, const float* __restrict__ g1, const float* __restrict__ be1,
    const float* __restrict__ m1, const float* __restrict__ v1,
    const float* __restrict__ b2, const float* __restrict__ g2, const float* __restrict__ be2,
    const float* __restrict__ m2, const float* __restrict__ v2,
    const float* __restrict__ b3, const float* __restrict__ g3, const float* __restrict__ be3,
    const float* __restrict__ m3, const float* __restrict__ v3,
    unsigned short* __restrict__ W1b, unsigned short* __restrict__ W2b,
    unsigned short* __restrict__ W3b, float* __restrict__ consts)
{
    const int idx = blockIdx.x * 256 + threadIdx.x;
    if (idx < 65536) {
        W1b[idx] = f2bf(W1[idx]);
        W2b[idx] = f2bf(W2[idx]);
        W3b[idx] = f2bf(W3[idx]);
    }
    if (idx < 768) {
        const int l = idx >> 8, c = idx & 255;
        const float* bp  = l == 0 ? b1  : (l == 1 ? b2  : b3);
        const float* gp  = l == 0 ? g1  : (l == 1 ? g2  : g3);
        const float* bep = l == 0 ? be1 : (l == 1 ? be2 : be3);
        const float* mp  = l == 0 ? m1  : (l == 1 ? m2  : m3);
        const float* vp  = l == 0 ? v1  : (l == 1 ? v2  : v3);
        const float s = gp[c] * rsqrtf(vp[c] + BN_EPS);
        consts[l * 768 + c]       = bp[c];
        consts[l * 768 + 256 + c] = s;
        consts[l * 768 + 512 + c] = bep[c] - mp[c] * s;
    }
}

// Fused: gather -> L1(GEMM+ReLU+BN) -> L2(GEMM+ReLU+BN) -> atomic-max scatter
__global__ __launch_bounds__(256) void msg_kernel(
    const float* __restrict__ x,
    const int* __restrict__ eidx,   // [2*E]: src row then tgt row
    int N, int E, int M,
    const unsigned short* __restrict__ W1b,
    const unsigned short* __restrict__ W2b,
    const float* __restrict__ consts,
    unsigned* __restrict__ agg)
{
    __shared__ unsigned short At[64 * ST];
    __shared__ int tgt_l[64];

    const int t = threadIdx.x;
    const int base = blockIdx.x * 64;

    // ---- gather: build A = [x_i | x_j - x_i] in bf16 ----
    {
        const int row = t >> 2, part = t & 3;
        const int msg = base + row;
        int si = -1, ti = -1;
        if (msg < E)      { si = eidx[msg]; ti = eidx[E + msg]; }
        else if (msg < M) { si = ti = msg - E; }
        if (part == 0) tgt_l[row] = ti;
        unsigned short* dst = &At[row * ST];
        const int c0 = part * 32;
        if (ti >= 0) {
            const float* xi = x + (size_t)ti * 128;
            const float* xj = x + (size_t)si * 128;
            #pragma unroll
            for (int c = c0; c < c0 + 32; c += 8) {
                float4 i0 = *(const float4*)(xi + c);
                float4 i1 = *(const float4*)(xi + c + 4);
                float4 j0 = *(const float4*)(xj + c);
                float4 j1 = *(const float4*)(xj + c + 4);
                uint4 pi, pd;
                pi.x = pk2(i0.x, i0.y); pi.y = pk2(i0.z, i0.w);
                pi.z = pk2(i1.x, i1.y); pi.w = pk2(i1.z, i1.w);
                pd.x = pk2(j0.x - i0.x, j0.y - i0.y);
                pd.y = pk2(j0.z - i0.z, j0.w - i0.w);
                pd.z = pk2(j1.x - i1.x, j1.y - i1.y);
                pd.w = pk2(j1.z - i1.z, j1.w - i1.w);
                *(uint4*)(dst + c) = pi;
                *(uint4*)(dst + 128 + c) = pd;
            }
        } else {
            const uint4 z = {0u, 0u, 0u, 0u};
            #pragma unroll
            for (int c = c0; c < c0 + 32; c += 8) {
                *(uint4*)(dst + c) = z;
                *(uint4*)(dst + 128 + c) = z;
            }
        }
    }
    __syncthreads();

    const int lane = t & 63;
    const int wv   = t >> 6;
    const int n16  = lane & 15;
    const int qd   = lane >> 4;
    const int wc   = wv * 64;          // this wave's 64 output cols

    const f32x4 vzero = {0.f, 0.f, 0.f, 0.f};
    f32x4 acc[4][4];
    #pragma unroll
    for (int i = 0; i < 4; i++)
        #pragma unroll
        for (int j = 0; j < 4; j++) acc[i][j] = vzero;

    // ---- GEMM1: At(64x256) @ W1^T cols[wc..wc+64) ----
    #pragma unroll
    for (int ks = 0; ks < 8; ks++) {
        const int k0 = ks * 32 + qd * 8;
        bf16x8 a[4];
        #pragma unroll
        for (int ri = 0; ri < 4; ri++)
            a[ri] = *(const bf16x8*)&At[(ri * 16 + n16) * ST + k0];
        #pragma unroll
        for (int ci = 0; ci < 4; ci++) {
            bf16x8 b = *(const bf16x8*)&W1b[(size_t)(wc + ci * 16 + n16) * 256 + k0];
            #pragma unroll
            for (int ri = 0; ri < 4; ri++)
                acc[ri][ci] = __builtin_amdgcn_mfma_f32_16x16x32_bf16(a[ri], b, acc[ri][ci], 0, 0, 0);
        }
    }
    __syncthreads();   // all A-reads done; safe to overwrite At

    // ---- epilogue1: bias+ReLU+BN -> bf16 back into At ----
    {
        const float* B1 = consts;
        const float* S1 = consts + 256;
        const float* T1 = consts + 512;
        #pragma unroll
        for (int ci = 0; ci < 4; ci++) {
            const int col = wc + ci * 16 + n16;
            const float bb = B1[col], ss = S1[col], tt = T1[col];
            #pragma unroll
            for (int ri = 0; ri < 4; ri++) {
                #pragma unroll
                for (int r = 0; r < 4; r++) {
                    const int row = ri * 16 + qd * 4 + r;
                    float v = fmaxf(acc[ri][ci][r] + bb, 0.f) * ss + tt;
                    At[row * ST + col] = f2bf(v);
                }
                acc[ri][ci] = vzero;
            }
        }
    }
    __syncthreads();

    // ---- GEMM2: h1 @ W2^T ----
    #pragma unroll
    for (int ks = 0; ks < 8; ks++) {
        const int k0 = ks * 32 + qd * 8;
        bf16x8 a[4];
        #pragma unroll
        for (int ri = 0; ri < 4; ri++)
            a[ri] = *(const bf16x8*)&At[(ri * 16 + n16) * ST + k0];
        #pragma unroll
        for (int ci = 0; ci < 4; ci++) {
            bf16x8 b = *(const bf16x8*)&W2b[(size_t)(wc + ci * 16 + n16) * 256 + k0];
            #pragma unroll
            for (int ri = 0; ri < 4; ri++)
                acc[ri][ci] = __builtin_amdgcn_mfma_f32_16x16x32_bf16(a[ri], b, acc[ri][ci], 0, 0, 0);
        }
    }

    // ---- epilogue2: bias+ReLU+BN -> atomic max scatter ----
    {
        const float* B2 = consts + 768;
        const float* S2 = consts + 768 + 256;
        const float* T2 = consts + 768 + 512;
        #pragma unroll
        for (int ci = 0; ci < 4; ci++) {
            const int col = wc + ci * 16 + n16;
            const float bb = B2[col], ss = S2[col], tt = T2[col];
            #pragma unroll
            for (int ri = 0; ri < 4; ri++) {
                #pragma unroll
                for (int r = 0; r < 4; r++) {
                    const int row = ri * 16 + qd * 4 + r;
                    const int node = tgt_l[row];
                    if (node >= 0) {
                        float v = fmaxf(acc[ri][ci][r] + bb, 0.f) * ss + tt;
                        atomicMax(&agg[(size_t)node * 256 + col], fkey(v));
                    }
                }
            }
        }
    }
}

// Final layer: decode agg -> GEMM3 -> bias+ReLU+BN -> fp32 out
__global__ __launch_bounds__(256) void out_kernel(
    const unsigned* __restrict__ agg, int N,
    const unsigned short* __restrict__ W3b,
    const float* __restrict__ consts,
    float* __restrict__ out)
{
    __shared__ unsigned short At[64 * ST];

    const int t = threadIdx.x;
    const int base = blockIdx.x * 64;

    {
        const int row = t >> 2, part = t & 3;
        const int node = base + row;
        unsigned short* dst = &At[row * ST];
        const int c0 = part * 64;
        if (node < N) {
            const unsigned* ap = agg + (size_t)node * 256;
            #pragma unroll
            for (int c = c0; c < c0 + 64; c += 4) {
                uint4 k4 = *(const uint4*)(ap + c);
                uint2 p;
                p.x = pk2(unkey(k4.x), unkey(k4.y));
                p.y = pk2(unkey(k4.z), unkey(k4.w));
                *(uint2*)(dst + c) = p;
            }
        } else {
            const uint2 z = {0u, 0u};
            #pragma unroll
            for (int c = c0; c < c0 + 64; c += 4) *(uint2*)(dst + c) = z;
        }
    }
    __syncthreads();

    const int lane = t & 63;
    const int wv   = t >> 6;
    const int n16  = lane & 15;
    const int qd   = lane >> 4;
    const int wc   = wv * 64;

    const f32x4 vzero = {0.f, 0.f, 0.f, 0.f};
    f32x4 acc[4][4];
    #pragma unroll
    for (int i = 0; i < 4; i++)
        #pragma unroll
        for (int j = 0; j < 4; j++) acc[i][j] = vzero;

    #pragma unroll
    for (int ks = 0; ks < 8; ks++) {
        const int k0 = ks * 32 + qd * 8;
        bf16x8 a[4];
        #pragma unroll
        for (int ri = 0; ri < 4; ri++)
            a[ri] = *(const bf16x8*)&At[(ri * 16 + n16) * ST + k0];
        #pragma unroll
        for (int ci = 0; ci < 4; ci++) {
            bf16x8 b = *(const bf16x8*)&W3b[(size_t)(wc + ci * 16 + n16) * 256 + k0];
            #pragma unroll
            for (int ri = 0; ri < 4; ri++)
                acc[ri][ci] = __builtin_amdgcn_mfma_f32_16x16x32_bf16(a[ri], b, acc[ri][ci], 0, 0, 0);
        }
    }

    {
        const float* B3 = consts + 1536;
        const float* S3 = consts + 1536 + 256;
        const float* T3 = consts + 1536 + 512;
        #pragma unroll
        for (int ci = 0; ci < 4; ci++) {
            const int col = wc + ci * 16 + n16;
            const float bb = B3[col], ss = S3[col], tt = T3[col];
            #pragma unroll
            for (int ri = 0; ri < 4; ri++) {
                #pragma unroll
                for (int r = 0; r < 4; r++) {
                    const int row = ri * 16 + qd * 4 + r;
                    const int node = base + row;
                    if (node < N) {
                        float v = fmaxf(acc[ri][ci][r] + bb, 0.f) * ss + tt;
                        out[(size_t)node * 256 + col] = v;
                    }
                }
            }
        }
    }
}

extern "C" void kernel_launch(void* const* d_in, const int* in_sizes, int n_in,
                              void* d_out, int out_size, void* d_ws, size_t ws_size,
                              hipStream_t stream)
{
    const float* x  = (const float*)d_in[0];
    const int* eidx = (const int*)d_in[1];
    const int N = in_sizes[0] / 128;
    const int E = in_sizes[1] / 2;
    const int M = E + N;

    char* ws = (char*)d_ws;
    unsigned short* W1b = (unsigned short*)(ws);
    unsigned short* W2b = (unsigned short*)(ws + 131072);
    unsigned short* W3b = (unsigned short*)(ws + 262144);
    float* consts       = (float*)(ws + 393216);          // 3*768 floats
    unsigned* agg       = (unsigned*)(ws + 402432);       // N*256 uint keys

    hipLaunchKernelGGL(prep_kernel, dim3(256), dim3(256), 0, stream,
        (const float*)d_in[2], (const float*)d_in[8], (const float*)d_in[14],
        (const float*)d_in[3], (const float*)d_in[4], (const float*)d_in[5],
        (const float*)d_in[6], (const float*)d_in[7],
        (const float*)d_in[9], (const float*)d_in[10], (const float*)d_in[11],
        (const float*)d_in[12], (const float*)d_in[13],
        (const float*)d_in[15], (const float*)d_in[16], (const float*)d_in[17],
        (const float*)d_in[18], (const float*)d_in[19],
        W1b, W2b, W3b, consts);

    hipMemsetAsync(agg, 0, (size_t)N * 256 * sizeof(unsigned), stream);

    hipLaunchKernelGGL(msg_kernel, dim3((M + 63) / 64), dim3(256), 0, stream,
        x, eidx, N, E, M, W1b, W2b, consts, agg);

    hipLaunchKernelGGL(out_kernel, dim3((N + 63) / 64), dim3(256), 0, stream,
        agg, N, W3b, consts, (float*)d_out);
}

// Round 2
// 711.047 us; speedup vs baseline: 1.2301x; 1.2301x over previous
//
#include <hip/hip_runtime.h>
#include <stdint.h>

#define BN_EPS 1e-5f
#define ST 264   // LDS row stride in bf16 elems: rows 16B-aligned, bank-skewed

typedef __bf16 bf16x8 __attribute__((ext_vector_type(8)));
typedef float  f32x4  __attribute__((ext_vector_type(4)));

__device__ __forceinline__ unsigned short f2bf(float f) {
    unsigned u = __float_as_uint(f);
    unsigned r = (u + 0x7FFFu + ((u >> 16) & 1u)) >> 16;
    return (unsigned short)r;
}
__device__ __forceinline__ unsigned pk2(float a, float b) {
    return (unsigned)f2bf(a) | ((unsigned)f2bf(b) << 16);
}
// order-preserving bf16(16-bit pattern) -> 16-bit key (monotone). 0 is below
// every real key (min finite maps to 0x007F), so 0-init == "empty".
__device__ __forceinline__ unsigned short bfkey(unsigned short h) {
    return (h & 0x8000u) ? (unsigned short)(~h) : (unsigned short)(h | 0x8000u);
}
__device__ __forceinline__ unsigned short unbfkey(unsigned short k) {
    return (k & 0x8000u) ? (unsigned short)(k & 0x7FFFu) : (unsigned short)(~k);
}

__global__ void prep_kernel(
    const float* __restrict__ W1, const float* __restrict__ W2, const float* __restrict__ W3,
    const float* __restrict__ b1, const float* __restrict__ g1, const float* __restrict__ be1,
    const float* __restrict__ m1, const float* __restrict__ v1,
    const float* __restrict__ b2, const float* __restrict__ g2, const float* __restrict__ be2,
    const float* __restrict__ m2, const float* __restrict__ v2,
    const float* __restrict__ b3, const float* __restrict__ g3, const float* __restrict__ be3,
    const float* __restrict__ m3, const float* __restrict__ v3,
    unsigned short* __restrict__ W1b, unsigned short* __restrict__ W2b,
    unsigned short* __restrict__ W3b, float* __restrict__ consts)
{
    const int idx = blockIdx.x * 256 + threadIdx.x;
    if (idx < 65536) {
        W1b[idx] = f2bf(W1[idx]);
        W2b[idx] = f2bf(W2[idx]);
        W3b[idx] = f2bf(W3[idx]);
    }
    if (idx < 768) {
        const int l = idx >> 8, c = idx & 255;
        const float* bp  = l == 0 ? b1  : (l == 1 ? b2  : b3);
        const float* gp  = l == 0 ? g1  : (l == 1 ? g2  : g3);
        const float* bep = l == 0 ? be1 : (l == 1 ? be2 : be3);
        const float* mp  = l == 0 ? m1  : (l == 1 ? m2  : m3);
        const float* vp  = l == 0 ? v1  : (l == 1 ? v2  : v3);
        const float s = gp[c] * rsqrtf(vp[c] + BN_EPS);
        consts[l * 768 + c]       = bp[c];
        consts[l * 768 + 256 + c] = s;
        consts[l * 768 + 512 + c] = bep[c] - mp[c] * s;
    }
}

// ---- counting sort of messages by target node ----
__global__ void hist_kernel(const int* __restrict__ eidx, int E, int M,
                            unsigned* __restrict__ count)
{
    const int i = blockIdx.x * 256 + threadIdx.x;
    if (i < M) {
        const int tgt = (i < E) ? eidx[E + i] : (i - E);
        atomicAdd(&count[tgt], 1u);
    }
}

__global__ __launch_bounds__(1024) void scan_kernel(
    const unsigned* __restrict__ count, unsigned* __restrict__ cursor, int N)
{
    __shared__ unsigned part[1024];
    const int t = threadIdx.x;
    const int per = (N + 1023) / 1024;
    const int b = t * per;
    unsigned s = 0;
    for (int i = 0; i < per; i++) if (b + i < N) s += count[b + i];
    part[t] = s;
    __syncthreads();
    for (int off = 1; off < 1024; off <<= 1) {
        unsigned v = (t >= off) ? part[t - off] : 0u;
        __syncthreads();
        part[t] += v;
        __syncthreads();
    }
    unsigned run = (t > 0) ? part[t - 1] : 0u;
    for (int i = 0; i < per; i++) {
        if (b + i < N) {
            unsigned c = count[b + i];
            cursor[b + i] = run;
            run += c;
        }
    }
}

__global__ void scatter_kernel(const int* __restrict__ eidx, int E, int M,
                               unsigned* __restrict__ cursor, int* __restrict__ sorted)
{
    const int i = blockIdx.x * 256 + threadIdx.x;
    if (i < M) {
        const int tgt = (i < E) ? eidx[E + i] : (i - E);
        const unsigned pos = atomicAdd(&cursor[tgt], 1u);
        sorted[pos] = i;
    }
}

// Fused: gather -> L1(GEMM+ReLU+BN) -> L2(GEMM+ReLU+BN) -> segmented max -> atomics
__global__ __launch_bounds__(256) void msg_kernel(
    const float* __restrict__ x,
    const int* __restrict__ eidx,   // [2*E]: src rows then tgt rows
    const int* __restrict__ sorted, // [M] message ids sorted by target
    int N, int E, int M,
    const unsigned short* __restrict__ W1b,
    const unsigned short* __restrict__ W2b,
    const float* __restrict__ consts,
    unsigned* __restrict__ agg)
{
    __shared__ unsigned short At[64 * ST];
    __shared__ int tgt_l[64];

    const int t = threadIdx.x;
    const int base = blockIdx.x * 64;

    // ---- gather: build A = [x_i | x_j - x_i] in bf16 (sorted-by-target order) ----
    {
        const int row = t >> 2, part = t & 3;
        const int slot = base + row;
        int si = -1, ti = -1;
        if (slot < M) {
            const int msg = sorted[slot];
            if (msg < E) { si = eidx[msg]; ti = eidx[E + msg]; }
            else         { si = ti = msg - E; }
        }
        if (part == 0) tgt_l[row] = ti;
        unsigned short* dst = &At[row * ST];
        const int c0 = part * 32;
        if (ti >= 0) {
            const float* xi = x + (size_t)ti * 128;
            const float* xj = x + (size_t)si * 128;
            #pragma unroll
            for (int c = c0; c < c0 + 32; c += 8) {
                float4 i0 = *(const float4*)(xi + c);
                float4 i1 = *(const float4*)(xi + c + 4);
                float4 j0 = *(const float4*)(xj + c);
                float4 j1 = *(const float4*)(xj + c + 4);
                uint4 pi, pd;
                pi.x = pk2(i0.x, i0.y); pi.y = pk2(i0.z, i0.w);
                pi.z = pk2(i1.x, i1.y); pi.w = pk2(i1.z, i1.w);
                pd.x = pk2(j0.x - i0.x, j0.y - i0.y);
                pd.y = pk2(j0.z - i0.z, j0.w - i0.w);
                pd.z = pk2(j1.x - i1.x, j1.y - i1.y);
                pd.w = pk2(j1.z - i1.z, j1.w - i1.w);
                *(uint4*)(dst + c) = pi;
                *(uint4*)(dst + 128 + c) = pd;
            }
        } else {
            const uint4 z = {0u, 0u, 0u, 0u};
            #pragma unroll
            for (int c = c0; c < c0 + 32; c += 8) {
                *(uint4*)(dst + c) = z;
                *(uint4*)(dst + 128 + c) = z;
            }
        }
    }
    __syncthreads();

    const int lane = t & 63;
    const int wv   = t >> 6;
    const int n16  = lane & 15;
    const int qd   = lane >> 4;
    const int wc   = wv * 64;          // this wave's 64 output cols

    const f32x4 vzero = {0.f, 0.f, 0.f, 0.f};
    f32x4 acc[4][4];
    #pragma unroll
    for (int i = 0; i < 4; i++)
        #pragma unroll
        for (int j = 0; j < 4; j++) acc[i][j] = vzero;

    // ---- GEMM1: At(64x256) @ W1^T cols[wc..wc+64) ----
    #pragma unroll
    for (int ks = 0; ks < 8; ks++) {
        const int k0 = ks * 32 + qd * 8;
        bf16x8 a[4];
        #pragma unroll
        for (int ri = 0; ri < 4; ri++)
            a[ri] = *(const bf16x8*)&At[(ri * 16 + n16) * ST + k0];
        #pragma unroll
        for (int ci = 0; ci < 4; ci++) {
            bf16x8 b = *(const bf16x8*)&W1b[(size_t)(wc + ci * 16 + n16) * 256 + k0];
            #pragma unroll
            for (int ri = 0; ri < 4; ri++)
                acc[ri][ci] = __builtin_amdgcn_mfma_f32_16x16x32_bf16(a[ri], b, acc[ri][ci], 0, 0, 0);
        }
    }
    __syncthreads();   // all A-reads done; safe to overwrite At

    // ---- epilogue1: bias+ReLU+BN -> bf16 back into At ----
    {
        const float* B1 = consts;
        const float* S1 = consts + 256;
        const float* T1 = consts + 512;
        #pragma unroll
        for (int ci = 0; ci < 4; ci++) {
            const int col = wc + ci * 16 + n16;
            const float bb = B1[col], ss = S1[col], tt = T1[col];
            #pragma unroll
            for (int ri = 0; ri < 4; ri++) {
                #pragma unroll
                for (int r = 0; r < 4; r++) {
                    const int row = ri * 16 + qd * 4 + r;
                    float v = fmaxf(acc[ri][ci][r] + bb, 0.f) * ss + tt;
                    At[row * ST + col] = f2bf(v);
                }
                acc[ri][ci] = vzero;
            }
        }
    }
    __syncthreads();

    // ---- GEMM2: h1 @ W2^T ----
    #pragma unroll
    for (int ks = 0; ks < 8; ks++) {
        const int k0 = ks * 32 + qd * 8;
        bf16x8 a[4];
        #pragma unroll
        for (int ri = 0; ri < 4; ri++)
            a[ri] = *(const bf16x8*)&At[(ri * 16 + n16) * ST + k0];
        #pragma unroll
        for (int ci = 0; ci < 4; ci++) {
            bf16x8 b = *(const bf16x8*)&W2b[(size_t)(wc + ci * 16 + n16) * 256 + k0];
            #pragma unroll
            for (int ri = 0; ri < 4; ri++)
                acc[ri][ci] = __builtin_amdgcn_mfma_f32_16x16x32_bf16(a[ri], b, acc[ri][ci], 0, 0, 0);
        }
    }
    __syncthreads();   // GEMM2 A-reads done; reuse At for keys

    // ---- epilogue2: bias+ReLU+BN -> 16-bit keys into At ----
    {
        const float* B2 = consts + 768;
        const float* S2 = consts + 768 + 256;
        const float* T2 = consts + 768 + 512;
        #pragma unroll
        for (int ci = 0; ci < 4; ci++) {
            const int col = wc + ci * 16 + n16;
            const float bb = B2[col], ss = S2[col], tt = T2[col];
            #pragma unroll
            for (int ri = 0; ri < 4; ri++) {
                #pragma unroll
                for (int r = 0; r < 4; r++) {
                    const int row = ri * 16 + qd * 4 + r;
                    float v = fmaxf(acc[ri][ci][r] + bb, 0.f) * ss + tt;
                    At[row * ST + col] = bfkey(f2bf(v));
                }
            }
        }
    }
    __syncthreads();

    // ---- segmented max over sorted rows: ~1 atomic per (segment, col) ----
    {
        const int c = t;  // thread owns one column
        int curT = -1;
        unsigned curK = 0;
        for (int r = 0; r < 64; r++) {
            const int tg = tgt_l[r];                 // wave-uniform broadcast
            const unsigned k = At[r * ST + c];
            if (tg != curT) {                        // wave-uniform branch
                if (curT >= 0) atomicMax(&agg[(size_t)curT * 256 + c], curK);
                curT = tg; curK = k;
            } else {
                curK = (k > curK) ? k : curK;
            }
        }
        if (curT >= 0) atomicMax(&agg[(size_t)curT * 256 + c], curK);
    }
}

// Final layer: decode agg keys -> GEMM3 -> bias+ReLU+BN -> fp32 out
__global__ __launch_bounds__(256) void out_kernel(
    const unsigned* __restrict__ agg, int N,
    const unsigned short* __restrict__ W3b,
    const float* __restrict__ consts,
    float* __restrict__ out)
{
    __shared__ unsigned short At[64 * ST];

    const int t = threadIdx.x;
    const int base = blockIdx.x * 64;

    {
        const int row = t >> 2, part = t & 3;
        const int node = base + row;
        unsigned short* dst = &At[row * ST];
        const int c0 = part * 64;
        if (node < N) {
            const unsigned* ap = agg + (size_t)node * 256;
            #pragma unroll
            for (int c = c0; c < c0 + 64; c += 4) {
                uint4 k4 = *(const uint4*)(ap + c);
                uint2 p;
                p.x = (unsigned)unbfkey((unsigned short)k4.x)
                    | ((unsigned)unbfkey((unsigned short)k4.y) << 16);
                p.y = (unsigned)unbfkey((unsigned short)k4.z)
                    | ((unsigned)unbfkey((unsigned short)k4.w) << 16);
                *(uint2*)(dst + c) = p;
            }
        } else {
            const uint2 z = {0u, 0u};
            #pragma unroll
            for (int c = c0; c < c0 + 64; c += 4) *(uint2*)(dst + c) = z;
        }
    }
    __syncthreads();

    const int lane = t & 63;
    const int wv   = t >> 6;
    const int n16  = lane & 15;
    const int qd   = lane >> 4;
    const int wc   = wv * 64;

    const f32x4 vzero = {0.f, 0.f, 0.f, 0.f};
    f32x4 acc[4][4];
    #pragma unroll
    for (int i = 0; i < 4; i++)
        #pragma unroll
        for (int j = 0; j < 4; j++) acc[i][j] = vzero;

    #pragma unroll
    for (int ks = 0; ks < 8; ks++) {
        const int k0 = ks * 32 + qd * 8;
        bf16x8 a[4];
        #pragma unroll
        for (int ri = 0; ri < 4; ri++)
            a[ri] = *(const bf16x8*)&At[(ri * 16 + n16) * ST + k0];
        #pragma unroll
        for (int ci = 0; ci < 4; ci++) {
            bf16x8 b = *(const bf16x8*)&W3b[(size_t)(wc + ci * 16 + n16) * 256 + k0];
            #pragma unroll
            for (int ri = 0; ri < 4; ri++)
                acc[ri][ci] = __builtin_amdgcn_mfma_f32_16x16x32_bf16(a[ri], b, acc[ri][ci], 0, 0, 0);
        }
    }

    {
        const float* B3 = consts + 1536;
        const float* S3 = consts + 1536 + 256;
        const float* T3 = consts + 1536 + 512;
        #pragma unroll
        for (int ci = 0; ci < 4; ci++) {
            const int col = wc + ci * 16 + n16;
            const float bb = B3[col], ss = S3[col], tt = T3[col];
            #pragma unroll
            for (int ri = 0; ri < 4; ri++) {
                #pragma unroll
                for (int r = 0; r < 4; r++) {
                    const int row = ri * 16 + qd * 4 + r;
                    const int node = base + row;
                    if (node < N) {
                        float v = fmaxf(acc[ri][ci][r] + bb, 0.f) * ss + tt;
                        out[(size_t)node * 256 + col] = v;
                    }
                }
            }
        }
    }
}

extern "C" void kernel_launch(void* const* d_in, const int* in_sizes, int n_in,
                              void* d_out, int out_size, void* d_ws, size_t ws_size,
                              hipStream_t stream)
{
    const float* x  = (const float*)d_in[0];
    const int* eidx = (const int*)d_in[1];
    const int N = in_sizes[0] / 128;
    const int E = in_sizes[1] / 2;
    const int M = E + N;

    char* ws = (char*)d_ws;
    unsigned short* W1b = (unsigned short*)(ws);
    unsigned short* W2b = (unsigned short*)(ws + 131072);
    unsigned short* W3b = (unsigned short*)(ws + 262144);
    float* consts       = (float*)(ws + 393216);          // 3*768 floats
    unsigned* agg       = (unsigned*)(ws + 402432);       // N*256 keys (20.48 MB)
    size_t off = 402432 + (size_t)N * 256 * sizeof(unsigned);
    unsigned* count     = (unsigned*)(ws + off); off += (size_t)N * sizeof(unsigned);
    unsigned* cursor    = (unsigned*)(ws + off); off += (size_t)N * sizeof(unsigned);
    int* sorted         = (int*)(ws + off);               // M ints

    hipLaunchKernelGGL(prep_kernel, dim3(256), dim3(256), 0, stream,
        (const float*)d_in[2], (const float*)d_in[8], (const float*)d_in[14],
        (const float*)d_in[3], (const float*)d_in[4], (const float*)d_in[5],
        (const float*)d_in[6], (const float*)d_in[7],
        (const float*)d_in[9], (const float*)d_in[10], (const float*)d_in[11],
        (const float*)d_in[12], (const float*)d_in[13],
        (const float*)d_in[15], (const float*)d_in[16], (const float*)d_in[17],
        (const float*)d_in[18], (const float*)d_in[19],
        W1b, W2b, W3b, consts);

    hipMemsetAsync(agg, 0, (size_t)N * 256 * sizeof(unsigned), stream);
    hipMemsetAsync(count, 0, (size_t)N * sizeof(unsigned), stream);

    hipLaunchKernelGGL(hist_kernel, dim3((M + 255) / 256), dim3(256), 0, stream,
        eidx, E, M, count);
    hipLaunchKernelGGL(scan_kernel, dim3(1), dim3(1024), 0, stream,
        count, cursor, N);
    hipLaunchKernelGGL(scatter_kernel, dim3((M + 255) / 256), dim3(256), 0, stream,
        eidx, E, M, cursor, sorted);

    hipLaunchKernelGGL(msg_kernel, dim3((M + 63) / 64), dim3(256), 0, stream,
        x, eidx, sorted, N, E, M, W1b, W2b, consts, agg);

    hipLaunchKernelGGL(out_kernel, dim3((N + 63) / 64), dim3(256), 0, stream,
        agg, N, W3b, consts, (float*)d_out);
}